// Round 19
// baseline (26226.471 us; speedup 1.0000x reference)
//
#include <hip/hip_runtime.h>
#include <math.h>

// Echo-state network: sequential scan with dense 2048x2048 matvec per step.
// R19 -- 8 time-chunks via BF16-PACKED W (the register-file cap was an fp32
// artifact):
//  - R18 floor analysis: per-round 1.51us is the structural latency floor of
//    the 256-block broadcast round; rounds (4144) were capped by fp32 W
//    register arithmetic (4 waves/SIMD x 128-reg cap < 128-float fragment).
//  - FIX: W fragment stored as RNE-rounded bf16 pairs: 4 rows x 8 x uint2 =
//    64 VGPRs. Total kernel ~110 regs <= launch_bounds(512,4)'s 128-reg cap
//    -> 2 blocks/CU co-residency GUARANTEED by resource arithmetic
//    (1024 thr <= 2048, 32KB LDS <= 160KB, 4 waves/SIMD x <=128 regs = 512).
//    -> 8 chunks x 64 blocks = 512 blocks; rounds 4144 -> 2104.
//  - Chunks are mutually independent (each starts from h=0; warm-up WUP=64),
//    so co-residency is only needed WITHIN a chunk. chunk = blk&7 puts each
//    chunk wholly on one XCD (64 blocks / 32 CUs) under blk%8 round-robin.
//  - Accuracy: bf16 W rel-err 2^-9 -> steady-state dh ~3e-3, dout ~1-3e-3;
//    absmax expected 3-8e-3 vs threshold 1.07e-2. Unpack = 1 VALU op per
//    weight (shl/and only -- no exotic builtins, guaranteed to compile).
//  - Uneven chunks equalize finish: chunk0 = 2104 outputs (no warm-up),
//    chunks1-7 = 2040 + 64 warm-up -> uniform 2104 rounds.
//  - Parity bias-tag: even chunks store h+2, odd h+6; poll accepts
//    |v-bias|<=1.25; memset-0 / 0xAA poison read not-ready. Adjacent-chunk
//    double-writes separated by ~2040 lockstep rounds.
//  - Per-round machinery = R5/R16 (proven optimal ordering): in-loop x load
//    drains with polls; block-cooperative poll (4 dwords/thr), straggler
//    retry, publish UNBIASED fp32 to LDS, ONE barrier, consume 8x
//    ds_read_b128 vs bf16-unpacked W, 7-shfl reduce, tanh, store.
//  - fc1/fc2 collapse: out = states_biased @ Mt + (c2b - bias_t * rm);
//    bias_t computed per-t in out_kernel (boundaries not %16).

#define SS 16384
#define II 64
#define RR 2048
#define HH 128
#define OO 50
#define OP 64          // padded output dim
#define NCH 8          // time chunks
#define NROUND 2104    // rounds per chunk (uniform)
#define C0LEN 2104     // chunk 0 output length
#define CLEN 2040      // chunks 1-7 output length
#define WUP 64         // warm-up steps for chunks 1-7
#define NBLK 512       // 8 chunks x 64 blocks
#define NTHR 512
#define TT 16          // timesteps per block in out_kernel

static const size_t STATES_BYTES = (size_t)SS * RR * 4;        // 134217728
static const size_t MT_OFF  = STATES_BYTES;
static const size_t C2B_OFF = MT_OFF + (size_t)RR * OP * 4;    // +524288
static const size_t RM_OFF  = C2B_OFF + 256;
static const size_t RS_OFF  = RM_OFF + 256;
static const size_t WS_NEED = RS_OFF + 512 + 256;

// Opaque register pin for LOOP-INVARIANT values (W fragments) only.
#define PIN2(q) asm volatile("" : "+v"((q).x), "+v"((q).y))

__device__ __forceinline__ unsigned bf16rne(float f) {
    const unsigned u = __float_as_uint(f);
    return (u + 0x7FFFu + ((u >> 16) & 1u)) >> 16;   // RNE to top-16
}
__device__ __forceinline__ float bf_lo(unsigned d) {   // low bf16 -> fp32
    return __uint_as_float(d << 16);
}
__device__ __forceinline__ float bf_hi(unsigned d) {   // high bf16 -> fp32
    return __uint_as_float(d & 0xFFFF0000u);
}

// ---------------------------------------------------------------------------
// Persistent chunked scan. chunk = blk&7 (whole chunk on one XCD),
// brow = blk>>3. Wave w owns rows R0=brow*32+w*4 .. R0+3; lane l holds cols
// {4l+j+256m} of its 4 rows as bf16 pairs (uint2 per (row, m)).
// ---------------------------------------------------------------------------
__global__ __launch_bounds__(NTHR, 4)
void scan_kernel(const float* __restrict__ x,
                 const float* __restrict__ Win,
                 const float* __restrict__ W,
                 float* __restrict__ states)
{
    const int tid   = threadIdx.x;
    const int blk   = blockIdx.x;
    const int wave  = tid >> 6;             // 0..7
    const int lane  = tid & 63;
    const int chunk = blk & 7;              // one XCD per chunk
    const int brow  = blk >> 3;             // 0..63
    const int R0    = brow * 32 + wave * 4;

    const float bias = (chunk & 1) ? 6.0f : 2.0f;
    // chunk 0: [0, 2104) no warm-up; chunk c>=1: g0 = 2104+(c-1)*2040-64
    const int g0 = (chunk == 0) ? 0 : (C0LEN + (chunk - 1) * CLEN - WUP);

    // W fragments: 4 rows x 8 (m) x 4 cols as bf16 pairs = 64 VGPRs, pinned.
    uint2 wq[4][8];
#pragma unroll
    for (int r = 0; r < 4; ++r)
#pragma unroll
        for (int m = 0; m < 8; ++m) {
            const float* wp = &W[(size_t)(R0 + r) * RR + 4 * lane + 256 * m];
            wq[r][m].x = bf16rne(wp[0]) | (bf16rne(wp[1]) << 16);
            wq[r][m].y = bf16rne(wp[2]) | (bf16rne(wp[3]) << 16);
            PIN2(wq[r][m]);
        }
    // Input projection fragments (fp32 exact)
    float win[4];
#pragma unroll
    for (int r = 0; r < 4; ++r)
        win[r] = Win[(size_t)(R0 + r) * II + lane];

    __shared__ float hbuf[2][RR];   // double-buffered UNBIASED h tile (16 KB)

    float hold = 0.f;               // lane tracks row R0 + (lane&3)

    for (int j = 0; j < NROUND; ++j) {
        const int g = g0 + j;
        const float xv = x[(size_t)g * II + lane];  // in-loop: drains w/ polls
        float a0 = win[0] * xv;
        float a1 = win[1] * xv;
        float a2 = win[2] * xv;
        float a3 = win[3] * xv;

        if (j > 0) {
            const float* hp = states + (size_t)(g - 1) * RR;
            float* sb = hbuf[(j - 1) & 1];
            // First pass: 4 coalesced dword poll loads per thread.
            float v0 = __hip_atomic_load(hp + tid,
                                         __ATOMIC_RELAXED, __HIP_MEMORY_SCOPE_AGENT);
            float v1 = __hip_atomic_load(hp + tid + 512,
                                         __ATOMIC_RELAXED, __HIP_MEMORY_SCOPE_AGENT);
            float v2 = __hip_atomic_load(hp + tid + 1024,
                                         __ATOMIC_RELAXED, __HIP_MEMORY_SCOPE_AGENT);
            float v3 = __hip_atomic_load(hp + tid + 1536,
                                         __ATOMIC_RELAXED, __HIP_MEMORY_SCOPE_AGENT);
            // Parity-range readiness: accept only my chunk's bias range.
            for (;;) {
                const bool r0 = fabsf(v0 - bias) <= 1.25f;
                const bool r1 = fabsf(v1 - bias) <= 1.25f;
                const bool r2 = fabsf(v2 - bias) <= 1.25f;
                const bool r3 = fabsf(v3 - bias) <= 1.25f;
                if (r0 && r1 && r2 && r3) break;
                if (!r0) v0 = __hip_atomic_load(hp + tid,
                                __ATOMIC_RELAXED, __HIP_MEMORY_SCOPE_AGENT);
                if (!r1) v1 = __hip_atomic_load(hp + tid + 512,
                                __ATOMIC_RELAXED, __HIP_MEMORY_SCOPE_AGENT);
                if (!r2) v2 = __hip_atomic_load(hp + tid + 1024,
                                __ATOMIC_RELAXED, __HIP_MEMORY_SCOPE_AGENT);
                if (!r3) v3 = __hip_atomic_load(hp + tid + 1536,
                                __ATOMIC_RELAXED, __HIP_MEMORY_SCOPE_AGENT);
            }
            // Publish UNBIASED values (stride-512: 2-way bank alias, free)
            sb[tid]        = v0 - bias;
            sb[tid + 512]  = v1 - bias;
            sb[tid + 1024] = v2 - bias;
            sb[tid + 1536] = v3 - bias;
            __syncthreads();           // the ONLY barrier per round

            // Consume: 8 x ds_read_b128 vs bf16-unpacked register W.
            const float4* sq = (const float4*)sb;
#pragma unroll
            for (int m = 0; m < 8; ++m) {
                const float4 q = sq[lane + 64 * m];
                a0 += bf_lo(wq[0][m].x) * q.x + bf_hi(wq[0][m].x) * q.y
                    + bf_lo(wq[0][m].y) * q.z + bf_hi(wq[0][m].y) * q.w;
                a1 += bf_lo(wq[1][m].x) * q.x + bf_hi(wq[1][m].x) * q.y
                    + bf_lo(wq[1][m].y) * q.z + bf_hi(wq[1][m].y) * q.w;
                a2 += bf_lo(wq[2][m].x) * q.x + bf_hi(wq[2][m].x) * q.y
                    + bf_lo(wq[2][m].y) * q.z + bf_hi(wq[2][m].y) * q.w;
                a3 += bf_lo(wq[3][m].x) * q.x + bf_hi(wq[3][m].x) * q.y
                    + bf_lo(wq[3][m].y) * q.z + bf_hi(wq[3][m].y) * q.w;
            }
        }

        // Reduce 4 rows: 2 fold stages + 4-level butterfly (7 shfls).
        {
            const float own01 = (lane & 1) ? a1 : a0;
            const float oth01 = (lane & 1) ? a0 : a1;
            const float u01   = own01 + __shfl_xor(oth01, 1, 64);
            const float own23 = (lane & 1) ? a3 : a2;
            const float oth23 = (lane & 1) ? a2 : a3;
            const float u23   = own23 + __shfl_xor(oth23, 1, 64);
            const float own   = (lane & 2) ? u23 : u01;
            const float oth   = (lane & 2) ? u01 : u23;
            float a = own + __shfl_xor(oth, 2, 64);
#pragma unroll
            for (int off = 4; off <= 32; off <<= 1)
                a += __shfl_xor(a, off, 64);
            // tanh + leaky update for row R0 + (lane&3)
            float u = fminf(fmaxf(a, -20.f), 20.f);
            const float e  = __expf(2.f * u);
            const float th = (e - 1.f) / (e + 1.f);
            const float hn = 0.5f * hold + 0.5f * th;
            hold = hn;
            if (lane < 4)
                __hip_atomic_store(&states[(size_t)g * RR + R0 + lane], hn + bias,
                                   __ATOMIC_RELAXED, __HIP_MEMORY_SCOPE_AGENT);
        }
    }
}

// ---------------------------------------------------------------------------
// rowsum of fc1_w rows: rs[h] = sum_r fc1_w[h][r]
// ---------------------------------------------------------------------------
__global__ void k_rowsum(const float* __restrict__ fc1w, float* __restrict__ rs)
{
    const int h = blockIdx.x;
    const int tid = threadIdx.x;
    float a = 0.f;
    for (int r = tid; r < RR; r += 256) a += fc1w[(size_t)h * RR + r];
#pragma unroll
    for (int off = 1; off <= 32; off <<= 1) a += __shfl_xor(a, off, 64);
    __shared__ float red[4];
    if ((tid & 63) == 0) red[tid >> 6] = a;
    __syncthreads();
    if (tid == 0) rs[h] = red[0] + red[1] + red[2] + red[3];
}

// ---------------------------------------------------------------------------
// Mt[r][o] = sum_h fc2_w[o][h] * fc1_w[h][r]   (o padded to 64, zeros)
// ---------------------------------------------------------------------------
__global__ void k_mt(const float* __restrict__ fc1w,
                     const float* __restrict__ fc2w,
                     float* __restrict__ Mt)
{
    __shared__ float w2[OO][HH + 1];
    const int o = threadIdx.x;         // 64
    const int r = blockIdx.x;          // 2048
    for (int i = o; i < OO * HH; i += 64) w2[i / HH][i % HH] = fc2w[i];
    __syncthreads();
    float a = 0.f;
    if (o < OO) {
        for (int h = 0; h < HH; ++h)
            a += w2[o][h] * fc1w[(size_t)h * RR + r];
    }
    Mt[r * OP + o] = a;
}

// ---------------------------------------------------------------------------
// c2b[o] = fc2_b[o] + sum_h fc2_w[o][h]*fc1_b[h];  rm[o] = sum_h fc2w*rs[h]
// ---------------------------------------------------------------------------
__global__ void k_cc(const float* __restrict__ fc2w,
                     const float* __restrict__ fc2b,
                     const float* __restrict__ fc1b,
                     const float* __restrict__ rs,
                     float* __restrict__ c2b,
                     float* __restrict__ rm)
{
    const int o = threadIdx.x;  // 64
    float a = 0.f, b = 0.f;
    if (o < OO) {
        for (int h = 0; h < HH; ++h) {
            a += fc2w[o * HH + h] * fc1b[h];
            b += fc2w[o * HH + h] * rs[h];
        }
        a += fc2b[o];
    }
    c2b[o] = a;
    rm[o]  = b;
}

// ---------------------------------------------------------------------------
// out[t][o] = sum_r Mt[r][o] * states_biased[t][r] + c2b[o] - bias_t*rm[o]
// bias_t computed per-t (chunk boundaries 2104 + k*2040, not %16).
// ---------------------------------------------------------------------------
__global__ __launch_bounds__(256)
void out_kernel(const float* __restrict__ sb,
                const float* __restrict__ Mt,
                const float* __restrict__ c2b,
                const float* __restrict__ rm,
                float* __restrict__ out)
{
    const int tid = threadIdx.x;
    const int o   = tid & 63;
    const int tl  = tid >> 6;          // 0..3
    const int t0  = blockIdx.x * TT;
    float acc[4] = {0.f, 0.f, 0.f, 0.f};
    const float* s0 = sb + (size_t)t0 * RR;

    for (int r = 0; r < RR; r += 4) {
        float4 sv0 = *(const float4*)(s0 + (size_t)(tl + 0)  * RR + r);
        float4 sv1 = *(const float4*)(s0 + (size_t)(tl + 4)  * RR + r);
        float4 sv2 = *(const float4*)(s0 + (size_t)(tl + 8)  * RR + r);
        float4 sv3 = *(const float4*)(s0 + (size_t)(tl + 12) * RR + r);
        float m0 = Mt[(r + 0) * OP + o];
        float m1 = Mt[(r + 1) * OP + o];
        float m2 = Mt[(r + 2) * OP + o];
        float m3 = Mt[(r + 3) * OP + o];
        acc[0] += m0 * sv0.x + m1 * sv0.y + m2 * sv0.z + m3 * sv0.w;
        acc[1] += m0 * sv1.x + m1 * sv1.y + m2 * sv1.z + m3 * sv1.w;
        acc[2] += m0 * sv2.x + m1 * sv2.y + m2 * sv2.z + m3 * sv2.w;
        acc[3] += m0 * sv3.x + m1 * sv3.y + m2 * sv3.z + m3 * sv3.w;
    }
    if (o < OO) {
        const float cb = c2b[o];
        const float rv = rm[o];
#pragma unroll
        for (int m = 0; m < 4; ++m) {
            const int t = t0 + tl + 4 * m;
            const int ch = (t < C0LEN) ? 0 : (1 + (t - C0LEN) / CLEN);
            const float bias = (ch & 1) ? 6.0f : 2.0f;
            out[(size_t)t * OO + o] = acc[m] + cb - bias * rv;
        }
    }
}

extern "C" void kernel_launch(void* const* d_in, const int* in_sizes, int n_in,
                              void* d_out, int out_size, void* d_ws, size_t ws_size,
                              hipStream_t stream)
{
    const float* x    = (const float*)d_in[0];
    const float* Win  = (const float*)d_in[1];
    const float* W    = (const float*)d_in[2];
    const float* fc1w = (const float*)d_in[3];
    const float* fc1b = (const float*)d_in[4];
    const float* fc2w = (const float*)d_in[5];
    const float* fc2b = (const float*)d_in[6];
    float* out = (float*)d_out;

    if (ws_size < WS_NEED) return;

    char*  ws     = (char*)d_ws;
    float* states = (float*)ws;
    float* Mt     = (float*)(ws + MT_OFF);
    float* c2b    = (float*)(ws + C2B_OFF);
    float* rm     = (float*)(ws + RM_OFF);
    float* rs     = (float*)(ws + RS_OFF);

    // Sentinel init: 0.0f is outside both bias ranges -> "not ready".
    hipMemsetAsync(states, 0, STATES_BYTES, stream);

    k_rowsum<<<HH, 256, 0, stream>>>(fc1w, rs);
    k_mt<<<RR, 64, 0, stream>>>(fc1w, fc2w, Mt);
    k_cc<<<1, 64, 0, stream>>>(fc2w, fc2b, fc1b, rs, c2b, rm);

    scan_kernel<<<NBLK, NTHR, 0, stream>>>(x, Win, W, states);

    out_kernel<<<SS / TT, 256, 0, stream>>>(states, Mt, c2b, rm, out);
}

// Round 20
// 6452.623 us; speedup vs baseline: 4.0645x; 4.0645x over previous
//
#include <hip/hip_runtime.h>
#include <math.h>

// Echo-state network: sequential scan with dense 2048x2048 matvec per step.
// R20 -- byte-exact revert to R16/R18 (best: 6.49/6.51ms, reproduced twice).
//
// R19 post-mortem (bf16-packed W, 8 chunks): VGPR_Count=64 + FETCH 60.9GB =
// the asm "v" pins forced the packed W into ARCH VGPRs (fp32 fragments in
// R11-R18 lived in AGPRs -- hence VGPR_Count~100 with 128 floats held);
// the 4-waves/EU arch-VGPR budget couldn't hold them -> scratch spill ->
// ~29MB/round of HBM spill traffic -> 26ms. 8-chunk is closed on every
// path: fp32 regs (arithmetic), bf16 regs (register-class spill), LDS
// (128KB x 2 blocks > 160KB), L2 refetch (282GB aggregate >> ceiling).
//
// Floor statement: the scan is LATENCY-bound (VALU 34%, HBM 0.9%, LDS
// conflicts 0) -- 4144 sequential 256-block LLC-broadcast rounds at
// ~1.51us each (store visibility ~500cy + batched detect ~1200-1800cy +
// consume/reduce ~500cy), within ~20% of the composed latency model; the
// residual is straggler jitter, and every de-jitter attempt (no-barrier
// R8/R10, prefetch R15/R17, pin R6, bigger blocks R7, 2-stream R13)
// measurably regressed. R16's ordering -- polls issued at round top,
// drained once together -- is the optimum under the in-order vmcnt FIFO.
//
// Structure (accumulated wins):
//  - 4 time-chunks x 64 blocks (R11): ESN forgetting => chunks 1-3 start
//    from h=0 with 64 warm-up steps (absmax bit-identical from WUP=2048
//    down to 64). Uneven chunks equalize finish: chunk0=4144 outputs,
//    chunks1-3=4080+64 -> uniform 4144 rounds. Boundaries 4144/8224/12304.
//  - 256 blocks x 512 thr, 1 block/CU: 4 rows/wave, W frag 128 floats/lane
//    pinned (lives in AGPRs; ~236 unified regs/wave = 2 waves/SIMD).
//  - XCD-affinity remap (R14): chunk = (blk&7)>>1.
//  - Parity bias-tag (R11): even chunks store h+2, odd h+6; poll accepts
//    |v-bias|<=1.25; memset-0 / 0xAA poison read not-ready.
//  - Per-round (R5/R16): in-loop x load drains with polls; block-coop poll
//    (4 dwords/thr), straggler retry, publish to LDS, ONE barrier, consume
//    8x ds_read_b128 vs register W, 7-shfl reduce, tanh, store.
//  - fc1/fc2 collapse: out = states_biased @ Mt + (c2b - bias_t * rm).

#define SS 16384
#define II 64
#define RR 2048
#define HH 128
#define OO 50
#define OP 64          // padded output dim
#define NROUND 4144    // rounds per chunk (uniform)
#define C0LEN 4144     // chunk 0 output length
#define CLEN 4080      // chunks 1-3 output length
#define WUP 64         // warm-up steps for chunks 1-3
#define NBLK 256
#define NTHR 512
#define TT 16          // timesteps per block in out_kernel

static const size_t STATES_BYTES = (size_t)SS * RR * 4;        // 134217728
static const size_t MT_OFF  = STATES_BYTES;
static const size_t C2B_OFF = MT_OFF + (size_t)RR * OP * 4;    // +524288
static const size_t RM_OFF  = C2B_OFF + 256;
static const size_t RS_OFF  = RM_OFF + 256;
static const size_t WS_NEED = RS_OFF + 512 + 256;

// Opaque register pin for LOOP-INVARIANT values (W fragments) only.
// NEVER on in-loop load results (forces a waitcnt at the pin site -- R6/R15).
#define PIN4(q) asm volatile("" : "+v"((q).x), "+v"((q).y), "+v"((q).z), "+v"((q).w))

// ---------------------------------------------------------------------------
// Persistent chunked scan. chunk = (blk&7)>>1 (XCD-pair affinity),
// brow = (blk>>3)*2 + (blk&1). Wave w owns rows R0=brow*32+w*4 .. R0+3;
// lane l holds cols {4l+j+256m} of its 4 rows.
// ---------------------------------------------------------------------------
__global__ __launch_bounds__(NTHR, 2)
void scan_kernel(const float* __restrict__ x,
                 const float* __restrict__ Win,
                 const float* __restrict__ W,
                 float* __restrict__ states)
{
    const int tid   = threadIdx.x;
    const int blk   = blockIdx.x;
    const int wave  = tid >> 6;             // 0..7
    const int lane  = tid & 63;
    const int chunk = (blk & 7) >> 1;       // XCD pair {2c, 2c+1}
    const int brow  = ((blk >> 3) << 1) | (blk & 1);   // 0..63
    const int R0    = brow * 32 + wave * 4;

    const float bias = (chunk & 1) ? 6.0f : 2.0f;
    // chunk 0: [0, 4144) no warm-up; chunk c>=1: g0 = 4144+(c-1)*4080-64
    const int g0 = (chunk == 0) ? 0 : (C0LEN + (chunk - 1) * CLEN - WUP);

    // W fragments: 4 rows x 8 float4 = 128 floats/lane, pinned.
    float4 wq[4][8];
#pragma unroll
    for (int r = 0; r < 4; ++r)
#pragma unroll
        for (int m = 0; m < 8; ++m) {
            wq[r][m] = *(const float4*)&W[(size_t)(R0 + r) * RR + 4 * lane + 256 * m];
            PIN4(wq[r][m]);
        }
    // Bias-fold: tw[r] = bias * sum of this lane's row-r fragment.
    float tw[4];
#pragma unroll
    for (int r = 0; r < 4; ++r) {
        float s = 0.f;
#pragma unroll
        for (int m = 0; m < 8; ++m)
            s += wq[r][m].x + wq[r][m].y + wq[r][m].z + wq[r][m].w;
        tw[r] = bias * s;
    }
    // Input projection fragments
    float win[4];
#pragma unroll
    for (int r = 0; r < 4; ++r)
        win[r] = Win[(size_t)(R0 + r) * II + lane];

    __shared__ float hbuf[2][RR];   // double-buffered biased h tile

    float hold = 0.f;               // lane tracks row R0 + (lane&3)

    for (int j = 0; j < NROUND; ++j) {
        const int g = g0 + j;
        const float xv = x[(size_t)g * II + lane];  // in-loop: drains with poll
        float a0 = win[0] * xv;
        float a1 = win[1] * xv;
        float a2 = win[2] * xv;
        float a3 = win[3] * xv;

        if (j > 0) {
            const float* hp = states + (size_t)(g - 1) * RR;
            float* sb = hbuf[(j - 1) & 1];
            // First pass: 4 coalesced dword poll loads per thread.
            float v0 = __hip_atomic_load(hp + tid,
                                         __ATOMIC_RELAXED, __HIP_MEMORY_SCOPE_AGENT);
            float v1 = __hip_atomic_load(hp + tid + 512,
                                         __ATOMIC_RELAXED, __HIP_MEMORY_SCOPE_AGENT);
            float v2 = __hip_atomic_load(hp + tid + 1024,
                                         __ATOMIC_RELAXED, __HIP_MEMORY_SCOPE_AGENT);
            float v3 = __hip_atomic_load(hp + tid + 1536,
                                         __ATOMIC_RELAXED, __HIP_MEMORY_SCOPE_AGENT);
            // Parity-range readiness: accept only my chunk's bias range.
            for (;;) {
                const bool r0 = fabsf(v0 - bias) <= 1.25f;
                const bool r1 = fabsf(v1 - bias) <= 1.25f;
                const bool r2 = fabsf(v2 - bias) <= 1.25f;
                const bool r3 = fabsf(v3 - bias) <= 1.25f;
                if (r0 && r1 && r2 && r3) break;
                if (!r0) v0 = __hip_atomic_load(hp + tid,
                                __ATOMIC_RELAXED, __HIP_MEMORY_SCOPE_AGENT);
                if (!r1) v1 = __hip_atomic_load(hp + tid + 512,
                                __ATOMIC_RELAXED, __HIP_MEMORY_SCOPE_AGENT);
                if (!r2) v2 = __hip_atomic_load(hp + tid + 1024,
                                __ATOMIC_RELAXED, __HIP_MEMORY_SCOPE_AGENT);
                if (!r3) v3 = __hip_atomic_load(hp + tid + 1536,
                                __ATOMIC_RELAXED, __HIP_MEMORY_SCOPE_AGENT);
            }
            // Publish raw biased values (stride-512: 2-way bank alias, free)
            sb[tid]        = v0;
            sb[tid + 512]  = v1;
            sb[tid + 1024] = v2;
            sb[tid + 1536] = v3;
            __syncthreads();           // the ONLY barrier per round

            a0 -= tw[0]; a1 -= tw[1]; a2 -= tw[2]; a3 -= tw[3];

            // Consume: 8 x ds_read_b128 vs register-held W (4 rows).
            const float4* sq = (const float4*)sb;
#pragma unroll
            for (int m = 0; m < 8; ++m) {
                const float4 q = sq[lane + 64 * m];
                a0 += wq[0][m].x * q.x + wq[0][m].y * q.y
                    + wq[0][m].z * q.z + wq[0][m].w * q.w;
                a1 += wq[1][m].x * q.x + wq[1][m].y * q.y
                    + wq[1][m].z * q.z + wq[1][m].w * q.w;
                a2 += wq[2][m].x * q.x + wq[2][m].y * q.y
                    + wq[2][m].z * q.z + wq[2][m].w * q.w;
                a3 += wq[3][m].x * q.x + wq[3][m].y * q.y
                    + wq[3][m].z * q.z + wq[3][m].w * q.w;
            }
        }

        // Reduce 4 rows: 2 fold stages + 4-level butterfly (7 shfls).
        {
            const float own01 = (lane & 1) ? a1 : a0;
            const float oth01 = (lane & 1) ? a0 : a1;
            const float u01   = own01 + __shfl_xor(oth01, 1, 64);
            const float own23 = (lane & 1) ? a3 : a2;
            const float oth23 = (lane & 1) ? a2 : a3;
            const float u23   = own23 + __shfl_xor(oth23, 1, 64);
            const float own   = (lane & 2) ? u23 : u01;
            const float oth   = (lane & 2) ? u01 : u23;
            float a = own + __shfl_xor(oth, 2, 64);
#pragma unroll
            for (int off = 4; off <= 32; off <<= 1)
                a += __shfl_xor(a, off, 64);
            // tanh + leaky update for row R0 + (lane&3)
            float u = fminf(fmaxf(a, -20.f), 20.f);
            const float e  = __expf(2.f * u);
            const float th = (e - 1.f) / (e + 1.f);
            const float hn = 0.5f * hold + 0.5f * th;
            hold = hn;
            if (lane < 4)
                __hip_atomic_store(&states[(size_t)g * RR + R0 + lane], hn + bias,
                                   __ATOMIC_RELAXED, __HIP_MEMORY_SCOPE_AGENT);
        }
    }
}

// ---------------------------------------------------------------------------
// rowsum of fc1_w rows: rs[h] = sum_r fc1_w[h][r]
// ---------------------------------------------------------------------------
__global__ void k_rowsum(const float* __restrict__ fc1w, float* __restrict__ rs)
{
    const int h = blockIdx.x;
    const int tid = threadIdx.x;
    float a = 0.f;
    for (int r = tid; r < RR; r += 256) a += fc1w[(size_t)h * RR + r];
#pragma unroll
    for (int off = 1; off <= 32; off <<= 1) a += __shfl_xor(a, off, 64);
    __shared__ float red[4];
    if ((tid & 63) == 0) red[tid >> 6] = a;
    __syncthreads();
    if (tid == 0) rs[h] = red[0] + red[1] + red[2] + red[3];
}

// ---------------------------------------------------------------------------
// Mt[r][o] = sum_h fc2_w[o][h] * fc1_w[h][r]   (o padded to 64, zeros)
// ---------------------------------------------------------------------------
__global__ void k_mt(const float* __restrict__ fc1w,
                     const float* __restrict__ fc2w,
                     float* __restrict__ Mt)
{
    __shared__ float w2[OO][HH + 1];
    const int o = threadIdx.x;         // 64
    const int r = blockIdx.x;          // 2048
    for (int i = o; i < OO * HH; i += 64) w2[i / HH][i % HH] = fc2w[i];
    __syncthreads();
    float a = 0.f;
    if (o < OO) {
        for (int h = 0; h < HH; ++h)
            a += w2[o][h] * fc1w[(size_t)h * RR + r];
    }
    Mt[r * OP + o] = a;
}

// ---------------------------------------------------------------------------
// c2b[o] = fc2_b[o] + sum_h fc2_w[o][h]*fc1_b[h];  rm[o] = sum_h fc2w*rs[h]
// ---------------------------------------------------------------------------
__global__ void k_cc(const float* __restrict__ fc2w,
                     const float* __restrict__ fc2b,
                     const float* __restrict__ fc1b,
                     const float* __restrict__ rs,
                     float* __restrict__ c2b,
                     float* __restrict__ rm)
{
    const int o = threadIdx.x;  // 64
    float a = 0.f, b = 0.f;
    if (o < OO) {
        for (int h = 0; h < HH; ++h) {
            a += fc2w[o * HH + h] * fc1b[h];
            b += fc2w[o * HH + h] * rs[h];
        }
        a += fc2b[o];
    }
    c2b[o] = a;
    rm[o]  = b;
}

// ---------------------------------------------------------------------------
// out[t][o] = sum_r Mt[r][o] * states_biased[t][r] + c2b[o] - bias_t*rm[o]
// Chunk boundaries 4144/8224/12304 are %16==0, so a 16-step tile is
// chunk-uniform.
// ---------------------------------------------------------------------------
__global__ __launch_bounds__(256)
void out_kernel(const float* __restrict__ sb,
                const float* __restrict__ Mt,
                const float* __restrict__ c2b,
                const float* __restrict__ rm,
                float* __restrict__ out)
{
    const int tid = threadIdx.x;
    const int o   = tid & 63;
    const int tl  = tid >> 6;          // 0..3
    const int t0  = blockIdx.x * TT;
    const int chunk = (t0 < C0LEN) ? 0 : (1 + (t0 - C0LEN) / CLEN);
    const float bias = (chunk & 1) ? 6.0f : 2.0f;
    float acc[4] = {0.f, 0.f, 0.f, 0.f};
    const float* s0 = sb + (size_t)t0 * RR;

    for (int r = 0; r < RR; r += 4) {
        float4 sv0 = *(const float4*)(s0 + (size_t)(tl + 0)  * RR + r);
        float4 sv1 = *(const float4*)(s0 + (size_t)(tl + 4)  * RR + r);
        float4 sv2 = *(const float4*)(s0 + (size_t)(tl + 8)  * RR + r);
        float4 sv3 = *(const float4*)(s0 + (size_t)(tl + 12) * RR + r);
        float m0 = Mt[(r + 0) * OP + o];
        float m1 = Mt[(r + 1) * OP + o];
        float m2 = Mt[(r + 2) * OP + o];
        float m3 = Mt[(r + 3) * OP + o];
        acc[0] += m0 * sv0.x + m1 * sv0.y + m2 * sv0.z + m3 * sv0.w;
        acc[1] += m0 * sv1.x + m1 * sv1.y + m2 * sv1.z + m3 * sv1.w;
        acc[2] += m0 * sv2.x + m1 * sv2.y + m2 * sv2.z + m3 * sv2.w;
        acc[3] += m0 * sv3.x + m1 * sv3.y + m2 * sv3.z + m3 * sv3.w;
    }
    if (o < OO) {
        const float cc = c2b[o] - bias * rm[o];
#pragma unroll
        for (int m = 0; m < 4; ++m) {
            const int t = t0 + tl + 4 * m;
            out[(size_t)t * OO + o] = acc[m] + cc;
        }
    }
}

extern "C" void kernel_launch(void* const* d_in, const int* in_sizes, int n_in,
                              void* d_out, int out_size, void* d_ws, size_t ws_size,
                              hipStream_t stream)
{
    const float* x    = (const float*)d_in[0];
    const float* Win  = (const float*)d_in[1];
    const float* W    = (const float*)d_in[2];
    const float* fc1w = (const float*)d_in[3];
    const float* fc1b = (const float*)d_in[4];
    const float* fc2w = (const float*)d_in[5];
    const float* fc2b = (const float*)d_in[6];
    float* out = (float*)d_out;

    if (ws_size < WS_NEED) return;

    char*  ws     = (char*)d_ws;
    float* states = (float*)ws;
    float* Mt     = (float*)(ws + MT_OFF);
    float* c2b    = (float*)(ws + C2B_OFF);
    float* rm     = (float*)(ws + RM_OFF);
    float* rs     = (float*)(ws + RS_OFF);

    // Sentinel init: 0.0f is outside both bias ranges -> "not ready".
    hipMemsetAsync(states, 0, STATES_BYTES, stream);

    k_rowsum<<<HH, 256, 0, stream>>>(fc1w, rs);
    k_mt<<<RR, 64, 0, stream>>>(fc1w, fc2w, Mt);
    k_cc<<<1, 64, 0, stream>>>(fc2w, fc2b, fc1b, rs, c2b, rm);

    scan_kernel<<<NBLK, NTHR, 0, stream>>>(x, Win, W, states);

    out_kernel<<<SS / TT, 256, 0, stream>>>(states, Mt, c2b, rm, out);
}